// Round 11
// baseline (256.604 us; speedup 1.0000x reference)
//
#include <hip/hip_runtime.h>
#include <hip/hip_bf16.h>

#define N_NODES 50000
#define N_EDGES 1600000
#define NEG_SLOPE 0.01f
#define WPAD 136   // k-stride (fp16) for LDS-staged W

#define NBKT 256   // dst buckets
#define BKTW 196   // bucket width: 196*256 = 50176 >= 50000
#define NBLK1 200  // pass-1 blocks
#define CHUNK1 8000 // 200*8000 = 1.6M edges exactly

typedef _Float16 v8h __attribute__((ext_vector_type(8)));
typedef _Float16 v2h __attribute__((ext_vector_type(2)));
typedef float v4f __attribute__((ext_vector_type(4)));

// ---------------------------------------------------------------------------
// proj: z[n, h*16+col] = sum_d x[n,d] * W[h,d,col], fp16 MFMA 16x16x32.
// (unchanged)
// ---------------------------------------------------------------------------
__global__ __launch_bounds__(256) void proj_mfma_kernel(
    const float* __restrict__ x,
    const float* __restrict__ W,
    _Float16* __restrict__ z)
{
    __shared__ _Float16 Wl[128 * WPAD];

    const int t = threadIdx.x;
    for (int i = t; i < 16384; i += 256) {
        const int h = i >> 11, k = (i >> 4) & 127, col = i & 15;
        Wl[(h * 16 + col) * WPAD + k] = (_Float16)W[i];
    }
    __syncthreads();

    const int wid = t >> 6;
    const int l   = t & 63;
    const int lc  = l & 15;
    const int kg  = l >> 4;

    const int nwaves = gridDim.x * 4;
    for (int tile = blockIdx.x * 4 + wid; tile < N_NODES / 16; tile += nwaves) {
        const int n0 = tile * 16;
        v4f acc[8];
#pragma unroll
        for (int ht = 0; ht < 8; ht++) acc[ht] = (v4f)0.f;

#pragma unroll
        for (int kb = 0; kb < 4; kb++) {
            const float4* xp = (const float4*)&x[(n0 + lc) * 128 + kb * 32 + kg * 8];
            const float4 xa = xp[0];
            const float4 xb = xp[1];
            v8h a;
            a[0] = (_Float16)xa.x; a[1] = (_Float16)xa.y;
            a[2] = (_Float16)xa.z; a[3] = (_Float16)xa.w;
            a[4] = (_Float16)xb.x; a[5] = (_Float16)xb.y;
            a[6] = (_Float16)xb.z; a[7] = (_Float16)xb.w;
#pragma unroll
            for (int ht = 0; ht < 8; ht++) {
                const v8h b = *(const v8h*)&Wl[(ht * 16 + lc) * WPAD + kb * 32 + kg * 8];
                acc[ht] = __builtin_amdgcn_mfma_f32_16x16x32_f16(a, b, acc[ht], 0, 0, 0);
            }
        }

        _Float16* zp = &z[(n0 + 4 * kg) * 128 + lc];
#pragma unroll
        for (int ht = 0; ht < 8; ht++)
#pragma unroll
            for (int i = 0; i < 4; i++)
                zp[i * 128 + ht * 16] = (_Float16)acc[ht][i];
    }
}

// ---------------------------------------------------------------------------
// score: s_src[n,h], s_dst[n,h] from fp16 z. (unchanged)
// ---------------------------------------------------------------------------
__global__ __launch_bounds__(256) void score_kernel(
    const _Float16* __restrict__ z,
    const float* __restrict__ a_src, const float* __restrict__ a_dst,
    float* __restrict__ s_src, float* __restrict__ s_dst)
{
    __shared__ float asl[128], adl[128];
    const int t = threadIdx.x;
    if (t < 128) { asl[t] = a_src[t]; adl[t] = a_dst[t]; }
    __syncthreads();

    const int idx = blockIdx.x * 256 + t;
    if (idx >= N_NODES * 8) return;
    const int n = idx >> 3, h = idx & 7;

    const v8h z0 = *(const v8h*)&z[n * 128 + h * 16];
    const v8h z1 = *(const v8h*)&z[n * 128 + h * 16 + 8];
    float ss = 0.f, sd = 0.f;
#pragma unroll
    for (int j = 0; j < 8; j++) {
        ss = fmaf((float)z0[j], asl[h * 16 + j], ss);
        sd = fmaf((float)z0[j], adl[h * 16 + j], sd);
    }
#pragma unroll
    for (int j = 0; j < 8; j++) {
        ss = fmaf((float)z1[j], asl[h * 16 + 8 + j], ss);
        sd = fmaf((float)z1[j], adl[h * 16 + 8 + j], sd);
    }
    s_src[idx] = ss;
    s_dst[idx] = sd;
}

// ---------------------------------------------------------------------------
// CSR build (unchanged): two-level bucket sort, block-local writes.
// ---------------------------------------------------------------------------
__global__ __launch_bounds__(256) void hist_bucket_kernel(
    const int* __restrict__ dst, int* __restrict__ bh)
{
    __shared__ int lhist[NBKT];
    const int t = threadIdx.x, blk = blockIdx.x;
    lhist[t] = 0;
    __syncthreads();
    const int e0 = blk * CHUNK1, e1 = e0 + CHUNK1;
    for (int e = e0 + t; e < e1; e += 256)
        atomicAdd(&lhist[(unsigned)dst[e] / BKTW], 1);
    __syncthreads();
    bh[t * NBLK1 + blk] = lhist[t];
}

__global__ __launch_bounds__(256) void scan_buckets_kernel(
    int* __restrict__ bh, int* __restrict__ btotal)
{
    __shared__ int sb[256];
    const int t = threadIdx.x, b = blockIdx.x;
    const int v = (t < NBLK1) ? bh[b * NBLK1 + t] : 0;
    sb[t] = v;
    __syncthreads();
    int x = v;
    for (int off = 1; off < 256; off <<= 1) {
        const int add = (t >= off) ? sb[t - off] : 0;
        __syncthreads();
        x += add;
        sb[t] = x;
        __syncthreads();
    }
    if (t < NBLK1) bh[b * NBLK1 + t] = x - v;
    if (t == 255) btotal[b] = x;
}

__global__ __launch_bounds__(256) void scan_totals_kernel(
    const int* __restrict__ btotal, int* __restrict__ bstart)
{
    __shared__ int sb[256];
    const int t = threadIdx.x;
    const int v = btotal[t];
    sb[t] = v;
    __syncthreads();
    int x = v;
    for (int off = 1; off < 256; off <<= 1) {
        const int add = (t >= off) ? sb[t - off] : 0;
        __syncthreads();
        x += add;
        sb[t] = x;
        __syncthreads();
    }
    bstart[t] = x - v;
    if (t == 255) bstart[256] = x;
}

__global__ __launch_bounds__(256) void scatter_bucket_kernel(
    const int* __restrict__ src, const int* __restrict__ dst,
    const int* __restrict__ bh, const int* __restrict__ bstart,
    int* __restrict__ gbuf)
{
    __shared__ int lbase[NBKT];
    __shared__ int lcur[NBKT];
    const int t = threadIdx.x, blk = blockIdx.x;
    lbase[t] = bstart[t] + bh[t * NBLK1 + blk];
    lcur[t] = 0;
    __syncthreads();
    const int e0 = blk * CHUNK1, e1 = e0 + CHUNK1;
    for (int e = e0 + t; e < e1; e += 256) {
        const int d = dst[e];
        const unsigned b = (unsigned)d / BKTW;
        const int ld = d - (int)b * BKTW;
        const int r = atomicAdd(&lcur[b], 1);
        gbuf[lbase[b] + r] = (ld << 16) | src[e];
    }
}

__global__ __launch_bounds__(256) void sort_bucket_kernel(
    const int* __restrict__ gbuf, const int* __restrict__ bstart,
    int* __restrict__ perm, int* __restrict__ rowp)
{
    __shared__ int lhist[NBKT];
    __shared__ int lscan[NBKT];
    __shared__ int lcur[NBKT];
    const int t = threadIdx.x, b = blockIdx.x;
    const int base = bstart[b];
    const int cnt  = bstart[b + 1] - base;
    const int n0   = b * BKTW;

    lhist[t] = 0;
    lcur[t] = 0;
    __syncthreads();
    for (int i = t; i < cnt; i += 256)
        atomicAdd(&lhist[gbuf[base + i] >> 16], 1);
    __syncthreads();

    const int v = lhist[t];
    lscan[t] = v;
    __syncthreads();
    int x = v;
    for (int off = 1; off < 256; off <<= 1) {
        const int add = (t >= off) ? lscan[t - off] : 0;
        __syncthreads();
        x += add;
        lscan[t] = x;
        __syncthreads();
    }
    const int excl = x - v;
    __syncthreads();
    lscan[t] = excl;

    const int n = n0 + t;
    if (t < BKTW && n < N_NODES) rowp[n] = base + excl;
    if (b == NBKT - 1 && t == 0) rowp[N_NODES] = bstart[NBKT];
    __syncthreads();

    for (int i = t; i < cnt; i += 256) {
        const int e = gbuf[base + i];
        const int ld = e >> 16;
        const int r = atomicAdd(&lcur[ld], 1);
        perm[base + lscan[ld] + r] = e & 0xFFFF;
    }
}

// ---------------------------------------------------------------------------
// edge_weight: wperm[p][h] = exp(leaky_relu(s_src[perm[p]][h] + s_dst[n][h]))
// stored as BF16 (same exponent range as fp32 -> no overflow; fp16 overflowed
// at exp(s)>65504 -> inf -> NaN, the R10 failure). Wave per node; coalesced
// stores; random s_src reads hit a 1.6MB L2-resident array.
// ---------------------------------------------------------------------------
__global__ __launch_bounds__(256) void edge_weight_kernel(
    const int* __restrict__ rowp, const int* __restrict__ perm,
    const float* __restrict__ s_src, const float* __restrict__ s_dst,
    __hip_bfloat16* __restrict__ wperm)
{
    const int wv = threadIdx.x >> 6;
    const int l  = threadIdx.x & 63;
    const int n  = blockIdx.x * 4 + wv;   // grid = N/4 exactly

    const int e8 = l >> 3;
    const int h8 = l & 7;

    const int start = rowp[n];
    const int end   = rowp[n + 1];
    const float sd  = s_dst[n * 8 + h8];

    for (int j0 = start; j0 < end; j0 += 8) {
        const int jj = j0 + e8;
        if (jj < end) {
            const int se = perm[jj];
            float s = s_src[se * 8 + h8] + sd;
            s = s > 0.f ? s : NEG_SLOPE * s;
            wperm[jj * 8 + h8] = __float2bfloat16(__expf(s));
        }
    }
}

// ---------------------------------------------------------------------------
// gather v6: wave per node, lane = channel pair (c0=2l, head h=l>>3). Weights
// precomputed -> inner loop is pure gather+FMA: per edge 2 broadcast L1 loads
// (se, w) + 1 coalesced z dword + 2 cvt + 3 fma. Unroll 8 with clamp+cndmask
// predication -> 8 independent z rows in flight per wave. No LDS, no
// barriers, no cross-lane reduce (wsum lane-redundant but free).
// ---------------------------------------------------------------------------
__global__ __launch_bounds__(256) void gather_kernel(
    const int* __restrict__ row_ptr, const int* __restrict__ perm,
    const __hip_bfloat16* __restrict__ wperm,
    const _Float16* __restrict__ z,
    float* __restrict__ out, const int apply_elu)
{
    const int wv = threadIdx.x >> 6;
    const int l  = threadIdx.x & 63;
    const int n  = blockIdx.x * 4 + wv;   // grid = N/4 exactly

    const int c0 = 2 * l;
    const int h  = l >> 3;

    const int start = row_ptr[n];
    const int end   = row_ptr[n + 1];

    float acc0 = 0.f, acc1 = 0.f, wsum = 0.f;

    for (int j0 = start; j0 < end; j0 += 8) {
#pragma unroll
        for (int k = 0; k < 8; k++) {
            const int jr = j0 + k;
            const int jj = (jr < end) ? jr : end - 1;   // safe clamp
            const int se = perm[jj];                    // broadcast (L1)
            float w = __bfloat162float(wperm[jj * 8 + h]); // broadcast (L1)
            w = (jr < end) ? w : 0.f;
            const v2h zv = *(const v2h*)&z[se * 128 + c0];
            wsum += w;
            acc0 = fmaf(w, (float)zv[0], acc0);
            acc1 = fmaf(w, (float)zv[1], acc1);
        }
    }

    const float inv = (end > start) ? 1.f / wsum : 0.f;
    float o0 = acc0 * inv;
    float o1 = acc1 * inv;
    if (apply_elu) {
        o0 = o0 > 0.f ? o0 : expm1f(o0);
        o1 = o1 > 0.f ? o1 : expm1f(o1);
    }
    *(float2*)&out[n * 128 + c0] = make_float2(o0, o1);
}

extern "C" void kernel_launch(void* const* d_in, const int* in_sizes, int n_in,
                              void* d_out, int out_size, void* d_ws, size_t ws_size,
                              hipStream_t stream) {
    const float* x    = (const float*)d_in[0];
    const int*   src  = (const int*)d_in[1];
    const int*   dst  = (const int*)d_in[2];
    const float* W1   = (const float*)d_in[3];
    const float* a1s  = (const float*)d_in[4];
    const float* a1d  = (const float*)d_in[5];
    const float* W2   = (const float*)d_in[6];
    const float* a2s  = (const float*)d_in[7];
    const float* a2d  = (const float*)d_in[8];
    float* out = (float*)d_out;

    // workspace carve
    char* p = (char*)d_ws;
    _Float16* z  = (_Float16*)p;  p += (size_t)N_NODES * 128 * 2;       // 12.8MB
    __hip_bfloat16* wperm = (__hip_bfloat16*)p; p += (size_t)N_EDGES * 8 * 2; // 25.6MB
    float* ssrc  = (float*)p;     p += (size_t)N_NODES * 8 * 4;         // 1.6MB
    float* sdst  = (float*)p;     p += (size_t)N_NODES * 8 * 4;         // 1.6MB
    int*   rowp  = (int*)p;       p += ((size_t)N_NODES + 4) * 4;       // 200KB
    int*   bh    = (int*)p;       p += (size_t)NBKT * NBLK1 * 4;        // 205KB
    int*   btot  = (int*)p;       p += (size_t)NBKT * 4;
    int*   bstart= (int*)p;       p += ((size_t)NBKT + 4) * 4;
    int*   gbuf  = (int*)p;       p += (size_t)N_EDGES * 4;             // 6.4MB
    int*   perm  = (int*)p;       p += (size_t)N_EDGES * 4;             // 6.4MB

    const int PROJ_GRID   = 391;
    const int SCORE_GRID  = (N_NODES * 8 + 255) / 256;
    const int NODE4_GRID  = N_NODES / 4;   // 12500 blocks x 4 waves

    // ---- CSR build (shared by both layers) ----
    hist_bucket_kernel<<<NBLK1, 256, 0, stream>>>(dst, bh);
    scan_buckets_kernel<<<NBKT, 256, 0, stream>>>(bh, btot);
    scan_totals_kernel<<<1, 256, 0, stream>>>(btot, bstart);
    scatter_bucket_kernel<<<NBLK1, 256, 0, stream>>>(src, dst, bh, bstart, gbuf);
    sort_bucket_kernel<<<NBKT, 256, 0, stream>>>(gbuf, bstart, perm, rowp);

    // ---- layer 1 ----
    proj_mfma_kernel<<<PROJ_GRID, 256, 0, stream>>>(x, W1, z);
    score_kernel<<<SCORE_GRID, 256, 0, stream>>>(z, a1s, a1d, ssrc, sdst);
    edge_weight_kernel<<<NODE4_GRID, 256, 0, stream>>>(rowp, perm, ssrc, sdst, wperm);
    gather_kernel<<<NODE4_GRID, 256, 0, stream>>>(rowp, perm, wperm, z, out, 1);

    // ---- layer 2 ----
    proj_mfma_kernel<<<PROJ_GRID, 256, 0, stream>>>(out, W2, z);
    score_kernel<<<SCORE_GRID, 256, 0, stream>>>(z, a2s, a2d, ssrc, sdst);
    edge_weight_kernel<<<NODE4_GRID, 256, 0, stream>>>(rowp, perm, ssrc, sdst, wperm);
    gather_kernel<<<NODE4_GRID, 256, 0, stream>>>(rowp, perm, wperm, z, out, 0);
}

// Round 12
// 228.346 us; speedup vs baseline: 1.1237x; 1.1237x over previous
//
#include <hip/hip_runtime.h>
#include <hip/hip_bf16.h>

#define N_NODES 50000
#define N_EDGES 1600000
#define NEG_SLOPE 0.01f
#define WPAD 136   // k-stride (fp16) for LDS-staged W

#define NBKT 256   // dst buckets
#define BKTW 196   // bucket width: 196*256 = 50176 >= 50000
#define NBLK1 200  // pass-1 blocks
#define CHUNK1 8000 // 200*8000 = 1.6M edges exactly

typedef _Float16 v8h __attribute__((ext_vector_type(8)));
typedef _Float16 v2h __attribute__((ext_vector_type(2)));
typedef float v4f __attribute__((ext_vector_type(4)));

// ---------------------------------------------------------------------------
// proj: z[n, h*16+col] = sum_d x[n,d] * W[h,d,col], fp16 MFMA 16x16x32.
// (unchanged from R6)
// ---------------------------------------------------------------------------
__global__ __launch_bounds__(256) void proj_mfma_kernel(
    const float* __restrict__ x,
    const float* __restrict__ W,
    _Float16* __restrict__ z)
{
    __shared__ _Float16 Wl[128 * WPAD];

    const int t = threadIdx.x;
    for (int i = t; i < 16384; i += 256) {
        const int h = i >> 11, k = (i >> 4) & 127, col = i & 15;
        Wl[(h * 16 + col) * WPAD + k] = (_Float16)W[i];
    }
    __syncthreads();

    const int wid = t >> 6;
    const int l   = t & 63;
    const int lc  = l & 15;
    const int kg  = l >> 4;

    const int nwaves = gridDim.x * 4;
    for (int tile = blockIdx.x * 4 + wid; tile < N_NODES / 16; tile += nwaves) {
        const int n0 = tile * 16;
        v4f acc[8];
#pragma unroll
        for (int ht = 0; ht < 8; ht++) acc[ht] = (v4f)0.f;

#pragma unroll
        for (int kb = 0; kb < 4; kb++) {
            const float4* xp = (const float4*)&x[(n0 + lc) * 128 + kb * 32 + kg * 8];
            const float4 xa = xp[0];
            const float4 xb = xp[1];
            v8h a;
            a[0] = (_Float16)xa.x; a[1] = (_Float16)xa.y;
            a[2] = (_Float16)xa.z; a[3] = (_Float16)xa.w;
            a[4] = (_Float16)xb.x; a[5] = (_Float16)xb.y;
            a[6] = (_Float16)xb.z; a[7] = (_Float16)xb.w;
#pragma unroll
            for (int ht = 0; ht < 8; ht++) {
                const v8h b = *(const v8h*)&Wl[(ht * 16 + lc) * WPAD + kb * 32 + kg * 8];
                acc[ht] = __builtin_amdgcn_mfma_f32_16x16x32_f16(a, b, acc[ht], 0, 0, 0);
            }
        }

        _Float16* zp = &z[(n0 + 4 * kg) * 128 + lc];
#pragma unroll
        for (int ht = 0; ht < 8; ht++)
#pragma unroll
            for (int i = 0; i < 4; i++)
                zp[i * 128 + ht * 16] = (_Float16)acc[ht][i];
    }
}

// ---------------------------------------------------------------------------
// score: s_src[n,h], s_dst[n,h] from fp16 z. (unchanged from R6)
// ---------------------------------------------------------------------------
__global__ __launch_bounds__(256) void score_kernel(
    const _Float16* __restrict__ z,
    const float* __restrict__ a_src, const float* __restrict__ a_dst,
    float* __restrict__ s_src, float* __restrict__ s_dst)
{
    __shared__ float asl[128], adl[128];
    const int t = threadIdx.x;
    if (t < 128) { asl[t] = a_src[t]; adl[t] = a_dst[t]; }
    __syncthreads();

    const int idx = blockIdx.x * 256 + t;
    if (idx >= N_NODES * 8) return;
    const int n = idx >> 3, h = idx & 7;

    const v8h z0 = *(const v8h*)&z[n * 128 + h * 16];
    const v8h z1 = *(const v8h*)&z[n * 128 + h * 16 + 8];
    float ss = 0.f, sd = 0.f;
#pragma unroll
    for (int j = 0; j < 8; j++) {
        ss = fmaf((float)z0[j], asl[h * 16 + j], ss);
        sd = fmaf((float)z0[j], adl[h * 16 + j], sd);
    }
#pragma unroll
    for (int j = 0; j < 8; j++) {
        ss = fmaf((float)z1[j], asl[h * 16 + 8 + j], ss);
        sd = fmaf((float)z1[j], adl[h * 16 + 8 + j], sd);
    }
    s_src[idx] = ss;
    s_dst[idx] = sd;
}

// ---------------------------------------------------------------------------
// CSR build (structure unchanged): two-level bucket sort, block-local writes.
// Only change: perm stores PRE-SCALED byte offsets (se*256 = z row offset).
// ---------------------------------------------------------------------------
__global__ __launch_bounds__(256) void hist_bucket_kernel(
    const int* __restrict__ dst, int* __restrict__ bh)
{
    __shared__ int lhist[NBKT];
    const int t = threadIdx.x, blk = blockIdx.x;
    lhist[t] = 0;
    __syncthreads();
    const int e0 = blk * CHUNK1, e1 = e0 + CHUNK1;
    for (int e = e0 + t; e < e1; e += 256)
        atomicAdd(&lhist[(unsigned)dst[e] / BKTW], 1);
    __syncthreads();
    bh[t * NBLK1 + blk] = lhist[t];
}

__global__ __launch_bounds__(256) void scan_buckets_kernel(
    int* __restrict__ bh, int* __restrict__ btotal)
{
    __shared__ int sb[256];
    const int t = threadIdx.x, b = blockIdx.x;
    const int v = (t < NBLK1) ? bh[b * NBLK1 + t] : 0;
    sb[t] = v;
    __syncthreads();
    int x = v;
    for (int off = 1; off < 256; off <<= 1) {
        const int add = (t >= off) ? sb[t - off] : 0;
        __syncthreads();
        x += add;
        sb[t] = x;
        __syncthreads();
    }
    if (t < NBLK1) bh[b * NBLK1 + t] = x - v;
    if (t == 255) btotal[b] = x;
}

__global__ __launch_bounds__(256) void scan_totals_kernel(
    const int* __restrict__ btotal, int* __restrict__ bstart)
{
    __shared__ int sb[256];
    const int t = threadIdx.x;
    const int v = btotal[t];
    sb[t] = v;
    __syncthreads();
    int x = v;
    for (int off = 1; off < 256; off <<= 1) {
        const int add = (t >= off) ? sb[t - off] : 0;
        __syncthreads();
        x += add;
        sb[t] = x;
        __syncthreads();
    }
    bstart[t] = x - v;
    if (t == 255) bstart[256] = x;
}

__global__ __launch_bounds__(256) void scatter_bucket_kernel(
    const int* __restrict__ src, const int* __restrict__ dst,
    const int* __restrict__ bh, const int* __restrict__ bstart,
    int* __restrict__ gbuf)
{
    __shared__ int lbase[NBKT];
    __shared__ int lcur[NBKT];
    const int t = threadIdx.x, blk = blockIdx.x;
    lbase[t] = bstart[t] + bh[t * NBLK1 + blk];
    lcur[t] = 0;
    __syncthreads();
    const int e0 = blk * CHUNK1, e1 = e0 + CHUNK1;
    for (int e = e0 + t; e < e1; e += 256) {
        const int d = dst[e];
        const unsigned b = (unsigned)d / BKTW;
        const int ld = d - (int)b * BKTW;
        const int r = atomicAdd(&lcur[b], 1);
        gbuf[lbase[b] + r] = (ld << 16) | src[e];
    }
}

__global__ __launch_bounds__(256) void sort_bucket_kernel(
    const int* __restrict__ gbuf, const int* __restrict__ bstart,
    int* __restrict__ perm, int* __restrict__ rowp)
{
    __shared__ int lhist[NBKT];
    __shared__ int lscan[NBKT];
    __shared__ int lcur[NBKT];
    const int t = threadIdx.x, b = blockIdx.x;
    const int base = bstart[b];
    const int cnt  = bstart[b + 1] - base;
    const int n0   = b * BKTW;

    lhist[t] = 0;
    lcur[t] = 0;
    __syncthreads();
    for (int i = t; i < cnt; i += 256)
        atomicAdd(&lhist[gbuf[base + i] >> 16], 1);
    __syncthreads();

    const int v = lhist[t];
    lscan[t] = v;
    __syncthreads();
    int x = v;
    for (int off = 1; off < 256; off <<= 1) {
        const int add = (t >= off) ? lscan[t - off] : 0;
        __syncthreads();
        x += add;
        lscan[t] = x;
        __syncthreads();
    }
    const int excl = x - v;
    __syncthreads();
    lscan[t] = excl;

    const int n = n0 + t;
    if (t < BKTW && n < N_NODES) rowp[n] = base + excl;
    if (b == NBKT - 1 && t == 0) rowp[N_NODES] = bstart[NBKT];
    __syncthreads();

    for (int i = t; i < cnt; i += 256) {
        const int e = gbuf[base + i];
        const int ld = e >> 16;
        const int r = atomicAdd(&lcur[ld], 1);
        perm[base + lscan[ld] + r] = (e & 0xFFFF) << 8;   // se*256 byte offset
    }
}

// ---------------------------------------------------------------------------
// gather v8: fused weights, wave-private, VALU-lean.
// Wave per node. Per 8-edge round:
//   phase A (lane = e8=l>>3, h8=l&7): off=perm[j0+e8] (pre-scaled se*256),
//     s = s_src[se*8+h8]+sd8 via one shift-addressed load; w=exp(leaky(s));
//     single cndmask masks the tail (w=0). 2 VMEM + ~7 VALU + 1 exp.
//   phase B (lane = channel pair c0=2l, head h=l>>3): offs+weights pulled via
//     __shfl (ds_bpermute -> DS pipe, not VALU); 8 coalesced z dwords (each
//     covers a full 256B row across the wave); 2 cvt + 3 fma per edge.
//     Branch-free (perm has 8 zeroed slack ints; w=0 kills OOB slots).
// No LDS, no barriers, no wperm traffic.
// ---------------------------------------------------------------------------
__global__ __launch_bounds__(256) void gather_kernel(
    const int* __restrict__ row_ptr, const int* __restrict__ perm,
    const char* __restrict__ zb,           // z as byte base
    const char* __restrict__ ssb,          // s_src as byte base
    const float* __restrict__ s_dst,
    float* __restrict__ out, const int apply_elu)
{
    const int wv = threadIdx.x >> 6;
    const int l  = threadIdx.x & 63;
    const int n  = blockIdx.x * 4 + wv;   // grid = N/4 exactly

    const int e8 = l >> 3;                // phase-A edge slot
    const int h8 = l & 7;                 // phase-A head
    const int h  = l >> 3;                // phase-B head (channels 2l,2l+1)

    const int start = row_ptr[n];
    const int end   = row_ptr[n + 1];
    const float sd8 = s_dst[n * 8 + h8];

    float acc0 = 0.f, acc1 = 0.f, wsum = 0.f;

    for (int j0 = start; j0 < end; j0 += 8) {
        // ---- phase A: weights for edges j0..j0+7 ----
        const int off = perm[j0 + e8];                    // se*256 (slack-safe)
        float s = *(const float*)(ssb + (off >> 3) + h8 * 4) + sd8;
        s = s > 0.f ? s : NEG_SLOPE * s;
        float w = __expf(s);
        w = (j0 + e8 < end) ? w : 0.f;

        // ---- phase B: pull offs, issue 8 z loads, then weights+FMA ----
        int offk[8];
#pragma unroll
        for (int k = 0; k < 8; k++) offk[k] = __shfl(off, k * 8 + h);
        v2h zv[8];
#pragma unroll
        for (int k = 0; k < 8; k++)
            zv[k] = *(const v2h*)(zb + offk[k] + 4 * l);
#pragma unroll
        for (int k = 0; k < 8; k++) {
            const float wk = __shfl(w, k * 8 + h);
            wsum += wk;
            acc0 = fmaf(wk, (float)zv[k][0], acc0);
            acc1 = fmaf(wk, (float)zv[k][1], acc1);
        }
    }

    const float inv = (end > start) ? 1.f / wsum : 0.f;
    float o0 = acc0 * inv;
    float o1 = acc1 * inv;
    if (apply_elu) {
        o0 = o0 > 0.f ? o0 : expm1f(o0);
        o1 = o1 > 0.f ? o1 : expm1f(o1);
    }
    *(float2*)&out[n * 128 + 2 * l] = make_float2(o0, o1);
}

extern "C" void kernel_launch(void* const* d_in, const int* in_sizes, int n_in,
                              void* d_out, int out_size, void* d_ws, size_t ws_size,
                              hipStream_t stream) {
    const float* x    = (const float*)d_in[0];
    const int*   src  = (const int*)d_in[1];
    const int*   dst  = (const int*)d_in[2];
    const float* W1   = (const float*)d_in[3];
    const float* a1s  = (const float*)d_in[4];
    const float* a1d  = (const float*)d_in[5];
    const float* W2   = (const float*)d_in[6];
    const float* a2s  = (const float*)d_in[7];
    const float* a2d  = (const float*)d_in[8];
    float* out = (float*)d_out;

    // workspace carve
    char* p = (char*)d_ws;
    _Float16* z  = (_Float16*)p;  p += (size_t)N_NODES * 128 * 2;       // 12.8MB
    float* ssrc  = (float*)p;     p += (size_t)N_NODES * 8 * 4;         // 1.6MB
    float* sdst  = (float*)p;     p += (size_t)N_NODES * 8 * 4;         // 1.6MB
    int*   rowp  = (int*)p;       p += ((size_t)N_NODES + 4) * 4;       // 200KB
    int*   bh    = (int*)p;       p += (size_t)NBKT * NBLK1 * 4;        // 205KB
    int*   btot  = (int*)p;       p += (size_t)NBKT * 4;
    int*   bstart= (int*)p;       p += ((size_t)NBKT + 4) * 4;
    int*   gbuf  = (int*)p;       p += (size_t)N_EDGES * 4;             // 6.4MB
    int*   perm  = (int*)p;       p += ((size_t)N_EDGES + 8) * 4;       // 6.4MB + slack

    const int PROJ_GRID   = 391;
    const int SCORE_GRID  = (N_NODES * 8 + 255) / 256;
    const int NODE4_GRID  = N_NODES / 4;   // 12500 blocks x 4 waves

    // ---- CSR build (shared by both layers) ----
    hipMemsetAsync(perm + N_EDGES, 0, 8 * 4, stream);   // zero slack (safe OOB reads)
    hist_bucket_kernel<<<NBLK1, 256, 0, stream>>>(dst, bh);
    scan_buckets_kernel<<<NBKT, 256, 0, stream>>>(bh, btot);
    scan_totals_kernel<<<1, 256, 0, stream>>>(btot, bstart);
    scatter_bucket_kernel<<<NBLK1, 256, 0, stream>>>(src, dst, bh, bstart, gbuf);
    sort_bucket_kernel<<<NBKT, 256, 0, stream>>>(gbuf, bstart, perm, rowp);

    // ---- layer 1 ----
    proj_mfma_kernel<<<PROJ_GRID, 256, 0, stream>>>(x, W1, z);
    score_kernel<<<SCORE_GRID, 256, 0, stream>>>(z, a1s, a1d, ssrc, sdst);
    gather_kernel<<<NODE4_GRID, 256, 0, stream>>>(rowp, perm, (const char*)z,
                                                  (const char*)ssrc, sdst, out, 1);

    // ---- layer 2 ----
    proj_mfma_kernel<<<PROJ_GRID, 256, 0, stream>>>(out, W2, z);
    score_kernel<<<SCORE_GRID, 256, 0, stream>>>(z, a2s, a2d, ssrc, sdst);
    gather_kernel<<<NODE4_GRID, 256, 0, stream>>>(rowp, perm, (const char*)z,
                                                  (const char*)ssrc, sdst, out, 0);
}

// Round 13
// 213.874 us; speedup vs baseline: 1.1998x; 1.0677x over previous
//
#include <hip/hip_runtime.h>
#include <hip/hip_bf16.h>

#define N_NODES 50000
#define N_EDGES 1600000
#define NEG_SLOPE 0.01f
#define WPAD 136   // k-stride (fp16) for LDS-staged W

#define NBKT 256   // dst buckets
#define BKTW 196   // bucket width: 196*256 = 50176 >= 50000
#define NBLK1 200  // pass-1 blocks
#define CHUNK1 8000 // 200*8000 = 1.6M edges exactly (8000 % 4 == 0)

typedef _Float16 v8h __attribute__((ext_vector_type(8)));
typedef _Float16 v2h __attribute__((ext_vector_type(2)));
typedef float v4f __attribute__((ext_vector_type(4)));

// ---------------------------------------------------------------------------
// proj: z[n, h*16+col] = sum_d x[n,d] * W[h,d,col], fp16 MFMA 16x16x32.
// Epilogue v2: stage the 16x128 tile in wave-private LDS (row stride 264B ->
// <=2-way banks on write and read-back), then store coalesced 4x dwordx4 per
// lane (replaces 32 scalar 2-B global stores per lane).
// ---------------------------------------------------------------------------
__global__ __launch_bounds__(256) void proj_mfma_kernel(
    const float* __restrict__ x,
    const float* __restrict__ W,
    _Float16* __restrict__ z)
{
    __shared__ _Float16 Wl[128 * WPAD];
    __shared__ _Float16 Zs[4][16][132];   // 132 fp16 = 264 B row stride

    const int t = threadIdx.x;
    for (int i = t; i < 16384; i += 256) {
        const int h = i >> 11, k = (i >> 4) & 127, col = i & 15;
        Wl[(h * 16 + col) * WPAD + k] = (_Float16)W[i];
    }
    __syncthreads();

    const int wid = t >> 6;
    const int l   = t & 63;
    const int lc  = l & 15;
    const int kg  = l >> 4;

    const int nwaves = gridDim.x * 4;
    for (int tile = blockIdx.x * 4 + wid; tile < N_NODES / 16; tile += nwaves) {
        const int n0 = tile * 16;
        v4f acc[8];
#pragma unroll
        for (int ht = 0; ht < 8; ht++) acc[ht] = (v4f)0.f;

#pragma unroll
        for (int kb = 0; kb < 4; kb++) {
            const float4* xp = (const float4*)&x[(n0 + lc) * 128 + kb * 32 + kg * 8];
            const float4 xa = xp[0];
            const float4 xb = xp[1];
            v8h a;
            a[0] = (_Float16)xa.x; a[1] = (_Float16)xa.y;
            a[2] = (_Float16)xa.z; a[3] = (_Float16)xa.w;
            a[4] = (_Float16)xb.x; a[5] = (_Float16)xb.y;
            a[6] = (_Float16)xb.z; a[7] = (_Float16)xb.w;
#pragma unroll
            for (int ht = 0; ht < 8; ht++) {
                const v8h b = *(const v8h*)&Wl[(ht * 16 + lc) * WPAD + kb * 32 + kg * 8];
                acc[ht] = __builtin_amdgcn_mfma_f32_16x16x32_f16(a, b, acc[ht], 0, 0, 0);
            }
        }

        // stage D (row = 4*kg+i, col = ht*16+lc) into wave-private LDS
#pragma unroll
        for (int ht = 0; ht < 8; ht++)
#pragma unroll
            for (int i = 0; i < 4; i++)
                Zs[wid][4 * kg + i][ht * 16 + lc] = (_Float16)acc[ht][i];

        // read back coalesced: lane -> row l>>2, 32-ch chunk (l&3)
        const int r = l >> 2, q = l & 3;
        const _Float16* zr = &Zs[wid][r][q * 32];
        _Float16* zg = &z[(n0 + r) * 128 + q * 32];
#pragma unroll
        for (int c = 0; c < 4; c++)
            *(v8h*)(zg + c * 8) = *(const v8h*)(zr + c * 8);
    }
}

// ---------------------------------------------------------------------------
// score: s_src[n,h], s_dst[n,h] from fp16 z. (unchanged)
// ---------------------------------------------------------------------------
__global__ __launch_bounds__(256) void score_kernel(
    const _Float16* __restrict__ z,
    const float* __restrict__ a_src, const float* __restrict__ a_dst,
    float* __restrict__ s_src, float* __restrict__ s_dst)
{
    __shared__ float asl[128], adl[128];
    const int t = threadIdx.x;
    if (t < 128) { asl[t] = a_src[t]; adl[t] = a_dst[t]; }
    __syncthreads();

    const int idx = blockIdx.x * 256 + t;
    if (idx >= N_NODES * 8) return;
    const int n = idx >> 3, h = idx & 7;

    const v8h z0 = *(const v8h*)&z[n * 128 + h * 16];
    const v8h z1 = *(const v8h*)&z[n * 128 + h * 16 + 8];
    float ss = 0.f, sd = 0.f;
#pragma unroll
    for (int j = 0; j < 8; j++) {
        ss = fmaf((float)z0[j], asl[h * 16 + j], ss);
        sd = fmaf((float)z0[j], adl[h * 16 + j], sd);
    }
#pragma unroll
    for (int j = 0; j < 8; j++) {
        ss = fmaf((float)z1[j], asl[h * 16 + 8 + j], ss);
        sd = fmaf((float)z1[j], adl[h * 16 + 8 + j], sd);
    }
    s_src[idx] = ss;
    s_dst[idx] = sd;
}

// ---------------------------------------------------------------------------
// CSR build: two-level bucket sort, block-local writes. v2: int4-vectorized
// edge reads in hist/scatter (4x fewer VMEM issues; within-bucket order
// permutation is harmless -- edge sums are commutative).
// ---------------------------------------------------------------------------
__global__ __launch_bounds__(256) void hist_bucket_kernel(
    const int* __restrict__ dst, int* __restrict__ bh)
{
    __shared__ int lhist[NBKT];
    const int t = threadIdx.x, blk = blockIdx.x;
    lhist[t] = 0;
    __syncthreads();
    const int4* d4 = (const int4*)(dst + blk * CHUNK1);
    for (int i = t; i < CHUNK1 / 4; i += 256) {
        const int4 d = d4[i];
        atomicAdd(&lhist[(unsigned)d.x / BKTW], 1);
        atomicAdd(&lhist[(unsigned)d.y / BKTW], 1);
        atomicAdd(&lhist[(unsigned)d.z / BKTW], 1);
        atomicAdd(&lhist[(unsigned)d.w / BKTW], 1);
    }
    __syncthreads();
    bh[t * NBLK1 + blk] = lhist[t];
}

__global__ __launch_bounds__(256) void scan_buckets_kernel(
    int* __restrict__ bh, int* __restrict__ btotal)
{
    __shared__ int sb[256];
    const int t = threadIdx.x, b = blockIdx.x;
    const int v = (t < NBLK1) ? bh[b * NBLK1 + t] : 0;
    sb[t] = v;
    __syncthreads();
    int x = v;
    for (int off = 1; off < 256; off <<= 1) {
        const int add = (t >= off) ? sb[t - off] : 0;
        __syncthreads();
        x += add;
        sb[t] = x;
        __syncthreads();
    }
    if (t < NBLK1) bh[b * NBLK1 + t] = x - v;
    if (t == 255) btotal[b] = x;
}

__global__ __launch_bounds__(256) void scan_totals_kernel(
    const int* __restrict__ btotal, int* __restrict__ bstart)
{
    __shared__ int sb[256];
    const int t = threadIdx.x;
    const int v = btotal[t];
    sb[t] = v;
    __syncthreads();
    int x = v;
    for (int off = 1; off < 256; off <<= 1) {
        const int add = (t >= off) ? sb[t - off] : 0;
        __syncthreads();
        x += add;
        sb[t] = x;
        __syncthreads();
    }
    bstart[t] = x - v;
    if (t == 255) bstart[256] = x;
}

__global__ __launch_bounds__(256) void scatter_bucket_kernel(
    const int* __restrict__ src, const int* __restrict__ dst,
    const int* __restrict__ bh, const int* __restrict__ bstart,
    int* __restrict__ gbuf)
{
    __shared__ int lbase[NBKT];
    __shared__ int lcur[NBKT];
    const int t = threadIdx.x, blk = blockIdx.x;
    lbase[t] = bstart[t] + bh[t * NBLK1 + blk];
    lcur[t] = 0;
    __syncthreads();
    const int4* s4 = (const int4*)(src + blk * CHUNK1);
    const int4* d4 = (const int4*)(dst + blk * CHUNK1);
    for (int i = t; i < CHUNK1 / 4; i += 256) {
        const int4 d = d4[i];
        const int4 s = s4[i];
#pragma unroll
        for (int u = 0; u < 4; u++) {
            const int dd = (u == 0) ? d.x : (u == 1) ? d.y : (u == 2) ? d.z : d.w;
            const int ss = (u == 0) ? s.x : (u == 1) ? s.y : (u == 2) ? s.z : s.w;
            const unsigned b = (unsigned)dd / BKTW;
            const int ld = dd - (int)b * BKTW;
            const int r = atomicAdd(&lcur[b], 1);
            gbuf[lbase[b] + r] = (ld << 16) | ss;
        }
    }
}

__global__ __launch_bounds__(256) void sort_bucket_kernel(
    const int* __restrict__ gbuf, const int* __restrict__ bstart,
    int* __restrict__ perm, int* __restrict__ rowp)
{
    __shared__ int lhist[NBKT];
    __shared__ int lscan[NBKT];
    __shared__ int lcur[NBKT];
    const int t = threadIdx.x, b = blockIdx.x;
    const int base = bstart[b];
    const int cnt  = bstart[b + 1] - base;
    const int n0   = b * BKTW;

    lhist[t] = 0;
    lcur[t] = 0;
    __syncthreads();
    for (int i = t; i < cnt; i += 256)
        atomicAdd(&lhist[gbuf[base + i] >> 16], 1);
    __syncthreads();

    const int v = lhist[t];
    lscan[t] = v;
    __syncthreads();
    int x = v;
    for (int off = 1; off < 256; off <<= 1) {
        const int add = (t >= off) ? lscan[t - off] : 0;
        __syncthreads();
        x += add;
        lscan[t] = x;
        __syncthreads();
    }
    const int excl = x - v;
    __syncthreads();
    lscan[t] = excl;

    const int n = n0 + t;
    if (t < BKTW && n < N_NODES) rowp[n] = base + excl;
    if (b == NBKT - 1 && t == 0) rowp[N_NODES] = bstart[NBKT];
    __syncthreads();

    for (int i = t; i < cnt; i += 256) {
        const int e = gbuf[base + i];
        const int ld = e >> 16;
        const int r = atomicAdd(&lcur[ld], 1);
        perm[base + lscan[ld] + r] = (e & 0xFFFF) << 8;   // se*256 byte offset
    }
}

// ---------------------------------------------------------------------------
// gather v8 (unchanged from R12 -- at the random-fetch fabric wall):
// fused weights, wave-private, shfl-distributed, byte-offset perm.
// ---------------------------------------------------------------------------
__global__ __launch_bounds__(256) void gather_kernel(
    const int* __restrict__ row_ptr, const int* __restrict__ perm,
    const char* __restrict__ zb,           // z as byte base
    const char* __restrict__ ssb,          // s_src as byte base
    const float* __restrict__ s_dst,
    float* __restrict__ out, const int apply_elu)
{
    const int wv = threadIdx.x >> 6;
    const int l  = threadIdx.x & 63;
    const int n  = blockIdx.x * 4 + wv;   // grid = N/4 exactly

    const int e8 = l >> 3;                // phase-A edge slot
    const int h8 = l & 7;                 // phase-A head
    const int h  = l >> 3;                // phase-B head (channels 2l,2l+1)

    const int start = row_ptr[n];
    const int end   = row_ptr[n + 1];
    const float sd8 = s_dst[n * 8 + h8];

    float acc0 = 0.f, acc1 = 0.f, wsum = 0.f;

    for (int j0 = start; j0 < end; j0 += 8) {
        // ---- phase A: weights for edges j0..j0+7 ----
        const int off = perm[j0 + e8];                    // se*256 (slack-safe)
        float s = *(const float*)(ssb + (off >> 3) + h8 * 4) + sd8;
        s = s > 0.f ? s : NEG_SLOPE * s;
        float w = __expf(s);
        w = (j0 + e8 < end) ? w : 0.f;

        // ---- phase B: pull offs, issue 8 z loads, then weights+FMA ----
        int offk[8];
#pragma unroll
        for (int k = 0; k < 8; k++) offk[k] = __shfl(off, k * 8 + h);
        v2h zv[8];
#pragma unroll
        for (int k = 0; k < 8; k++)
            zv[k] = *(const v2h*)(zb + offk[k] + 4 * l);
#pragma unroll
        for (int k = 0; k < 8; k++) {
            const float wk = __shfl(w, k * 8 + h);
            wsum += wk;
            acc0 = fmaf(wk, (float)zv[k][0], acc0);
            acc1 = fmaf(wk, (float)zv[k][1], acc1);
        }
    }

    const float inv = (end > start) ? 1.f / wsum : 0.f;
    float o0 = acc0 * inv;
    float o1 = acc1 * inv;
    if (apply_elu) {
        o0 = o0 > 0.f ? o0 : expm1f(o0);
        o1 = o1 > 0.f ? o1 : expm1f(o1);
    }
    *(float2*)&out[n * 128 + 2 * l] = make_float2(o0, o1);
}

extern "C" void kernel_launch(void* const* d_in, const int* in_sizes, int n_in,
                              void* d_out, int out_size, void* d_ws, size_t ws_size,
                              hipStream_t stream) {
    const float* x    = (const float*)d_in[0];
    const int*   src  = (const int*)d_in[1];
    const int*   dst  = (const int*)d_in[2];
    const float* W1   = (const float*)d_in[3];
    const float* a1s  = (const float*)d_in[4];
    const float* a1d  = (const float*)d_in[5];
    const float* W2   = (const float*)d_in[6];
    const float* a2s  = (const float*)d_in[7];
    const float* a2d  = (const float*)d_in[8];
    float* out = (float*)d_out;

    // workspace carve
    char* p = (char*)d_ws;
    _Float16* z  = (_Float16*)p;  p += (size_t)N_NODES * 128 * 2;       // 12.8MB
    float* ssrc  = (float*)p;     p += (size_t)N_NODES * 8 * 4;         // 1.6MB
    float* sdst  = (float*)p;     p += (size_t)N_NODES * 8 * 4;         // 1.6MB
    int*   rowp  = (int*)p;       p += ((size_t)N_NODES + 4) * 4;       // 200KB
    int*   bh    = (int*)p;       p += (size_t)NBKT * NBLK1 * 4;        // 205KB
    int*   btot  = (int*)p;       p += (size_t)NBKT * 4;
    int*   bstart= (int*)p;       p += ((size_t)NBKT + 4) * 4;
    int*   gbuf  = (int*)p;       p += (size_t)N_EDGES * 4;             // 6.4MB
    int*   perm  = (int*)p;       p += ((size_t)N_EDGES + 8) * 4;       // 6.4MB + slack

    const int PROJ_GRID   = 391;
    const int SCORE_GRID  = (N_NODES * 8 + 255) / 256;
    const int NODE4_GRID  = N_NODES / 4;   // 12500 blocks x 4 waves

    // ---- CSR build (shared by both layers) ----
    hipMemsetAsync(perm + N_EDGES, 0, 8 * 4, stream);   // zero slack (safe OOB reads)
    hist_bucket_kernel<<<NBLK1, 256, 0, stream>>>(dst, bh);
    scan_buckets_kernel<<<NBKT, 256, 0, stream>>>(bh, btot);
    scan_totals_kernel<<<1, 256, 0, stream>>>(btot, bstart);
    scatter_bucket_kernel<<<NBLK1, 256, 0, stream>>>(src, dst, bh, bstart, gbuf);
    sort_bucket_kernel<<<NBKT, 256, 0, stream>>>(gbuf, bstart, perm, rowp);

    // ---- layer 1 ----
    proj_mfma_kernel<<<PROJ_GRID, 256, 0, stream>>>(x, W1, z);
    score_kernel<<<SCORE_GRID, 256, 0, stream>>>(z, a1s, a1d, ssrc, sdst);
    gather_kernel<<<NODE4_GRID, 256, 0, stream>>>(rowp, perm, (const char*)z,
                                                  (const char*)ssrc, sdst, out, 1);

    // ---- layer 2 ----
    proj_mfma_kernel<<<PROJ_GRID, 256, 0, stream>>>(out, W2, z);
    score_kernel<<<SCORE_GRID, 256, 0, stream>>>(z, a2s, a2d, ssrc, sdst);
    gather_kernel<<<NODE4_GRID, 256, 0, stream>>>(rowp, perm, (const char*)z,
                                                  (const char*)ssrc, sdst, out, 0);
}